// Round 1
// baseline (856.878 us; speedup 1.0000x reference)
//
#include <hip/hip_runtime.h>
#include <hip/hip_bf16.h>
#include <stdint.h>

#define S_DIM 2048
#define B_DIM 16
#define H2_DIM 2048
#define V_DIM 1024
#define M_DIM (S_DIM * B_DIM)   // 32768
#define K_HALF 2048
#define K_TOT 4096

typedef __attribute__((ext_vector_type(8))) short s16x8;   // 8 bf16 (4 VGPRs) MFMA frag
typedef __attribute__((ext_vector_type(4))) float f32x4;   // MFMA accumulator

// fp32 -> bf16 round-to-nearest-even (scalar, used in transposeB only)
__device__ __forceinline__ uint16_t f2bf(float f) {
    union { float f; uint32_t u; } c; c.f = f;
    uint32_t u = c.u;
    u += 0x7fffu + ((u >> 16) & 1u);
    return (uint16_t)(u >> 16);
}

// pack 2 fp32 -> 2 bf16 (round-to-nearest), 3 VALU ops: 2 adds + 1 v_perm_b32
__device__ __forceinline__ uint32_t pack_bf16_rn(float a, float b) {
    union { float f; uint32_t u; } ca, cb; ca.f = a; cb.f = b;
    uint32_t ua = ca.u + 0x8000u;
    uint32_t ub = cb.u + 0x8000u;
    return __builtin_amdgcn_perm(ub, ua, 0x07060302u);
}

__device__ __forceinline__ float fast_tanh(float x) {
    float e = __expf(2.0f * x);
    return 1.0f - 2.0f / (e + 1.0f);
}

// async global->LDS, 16B per lane. LDS dest is wave-uniform base + lane*16.
__device__ __forceinline__ void gload_lds16(const void* g, void* l) {
    __builtin_amdgcn_global_load_lds(
        (__attribute__((address_space(1))) void*)(uintptr_t)g,
        (__attribute__((address_space(3))) void*)(uint32_t)(uintptr_t)l,
        16, 0, 0);
}

// ------------- transpose+convert Ww/Wz [K][V] fp32 -> B^T [V][K] bf16 -------------
__global__ void transposeB(const float* __restrict__ Ww, const float* __restrict__ Wz,
                           uint16_t* __restrict__ B1, uint16_t* __restrict__ B2) {
    __shared__ float tile[32][33];
    const float* src = blockIdx.z ? Wz : Ww;
    uint16_t* dst = blockIdx.z ? B2 : B1;
    int k0 = blockIdx.x * 32, v0 = blockIdx.y * 32;
    int tv = threadIdx.x & 31, tk = threadIdx.x >> 5;  // tk in 0..7
#pragma unroll
    for (int r = 0; r < 4; r++) {
        int k = tk * 4 + r;
        tile[k][tv] = src[(size_t)(k0 + k) * V_DIM + v0 + tv];
    }
    __syncthreads();
#pragma unroll
    for (int r = 0; r < 4; r++) {
        int v = tk * 4 + r;
        dst[(size_t)(v0 + v) * K_HALF + k0 + tv] = f2bf(tile[tv][v]);
    }
}

// ---------------------------------- fused GEMM ----------------------------------
// 256x256 tile, 8 waves (2m x 4n), per-wave 128m x 64n, BK=64, 4-subphase schedule
// (8-phase template shape: ds_read subtile -> barrier -> lgkmcnt(0) -> setprio+16
// MFMA -> barrier). A(t+1) fp32 prefetched to regs at P0, packed+swizzle-written at
// P3; B(t+1) via global_load_lds issued at P0, in flight across all phase barriers,
// drained once per tile at P3 (~3 phases after issue => effectively non-blocking).
// Epilogue: u[m] += sum_n tanh(C[m,n]+bias[n]) * Vw[n]
__global__ __launch_bounds__(512, 2) void gemm_kernel(
    const float* __restrict__ F1, const float* __restrict__ F2,
    const uint16_t* __restrict__ B1, const uint16_t* __restrict__ B2,
    const float* __restrict__ bw, const float* __restrict__ bz,
    const float* __restrict__ wa_p, const float* __restrict__ Vw,
    float* __restrict__ u) {
    __shared__ __align__(16) uint16_t lA[2][256 * 64];   // 2 x 32 KB
    __shared__ __align__(16) uint16_t lB[2][256 * 64];   // 2 x 32 KB

    const int tid = threadIdx.x;
    const int lane = tid & 63;
    const int wv = tid >> 6;                      // wave 0..7, 2m x 4n grid
    const int wm = (wv >> 2) * 128, wn = (wv & 3) * 64;
    // XCD swizzle: the 4 n-tiles of an m-tile share id&7 -> same XCD -> A K-slices
    // stay L2-warm. 512 blocks = 2 exact dispatch rounds at 1 block/CU.
    const int id = blockIdx.x;                    // grid = 512
    const int nBase = ((id >> 3) & 3) * 256;
    const int mBase = ((id & 7) + ((id >> 5) << 3)) * 256;
    const int lr = lane >> 3;                     // row within 8-row staging group
    const int lc = lane & 7;                      // LDS chunk slot
    const int cg = lc ^ lr;                       // swizzled global chunk
    const int col = lane & 15, quad = lane >> 4;

    f32x4 acc[8][4] = {};

    // staging base pointers (this thread's fixed row/chunk assignment)
    const float* aRow[2];
    const uint16_t* bRow[2];
    {
        const size_t aoff = (size_t)(mBase + wv * 32 + lr) * K_HALF + cg * 8;
        aRow[0] = F1 + aoff; aRow[1] = F2 + aoff;
        const size_t boff = (size_t)(nBase + wv * 32 + lr) * K_HALF + cg * 8;
        bRow[0] = B1 + boff; bRow[1] = B2 + boff;
    }

    float4 ar[4][2];   // A prefetch registers (one K-tile ahead)

    auto loadA = [&](int kb) {
        const float* base = aRow[kb >> 11] + (kb & (K_HALF - 1));
#pragma unroll
        for (int j = 0; j < 4; j++) {
            const float* gp = base + (size_t)(j * 8) * K_HALF;
            ar[j][0] = ((const float4*)gp)[0];
            ar[j][1] = ((const float4*)gp)[1];
        }
    };
    auto issueB = [&](int kb, int p) {
        const uint16_t* base = bRow[kb >> 11] + (kb & (K_HALF - 1));
#pragma unroll
        for (int j = 0; j < 4; j++)
            gload_lds16(base + (size_t)(j * 8) * K_HALF, &lB[p][(wv * 32 + j * 8) * 64]);
    };
    auto packA = [&](int p) {
#pragma unroll
        for (int j = 0; j < 4; j++) {
            uint4 w = make_uint4(pack_bf16_rn(ar[j][0].x, ar[j][0].y),
                                 pack_bf16_rn(ar[j][0].z, ar[j][0].w),
                                 pack_bf16_rn(ar[j][1].x, ar[j][1].y),
                                 pack_bf16_rn(ar[j][1].z, ar[j][1].w));
            *(uint4*)&lA[p][(wv * 32 + j * 8 + lr) * 64 + lc * 8] = w;
        }
    };
    // LDS[row][chunk c] holds global chunk c ^ (row&7): read with the same XOR
    auto frag = [&](const uint16_t* l, int row, int cidx) -> s16x8 {
        return *(const s16x8*)&l[row * 64 + ((cidx ^ (row & 7)) << 3)];
    };

    // prologue: fill buffer 0
    loadA(0);
    issueB(0, 0);
    packA(0);   // compiler auto-waits the A loads
    asm volatile("s_waitcnt vmcnt(0) lgkmcnt(0)" ::: "memory");
    __builtin_amdgcn_s_barrier();

#pragma unroll 1
    for (int t = 0; t < 64; ++t) {
        const int p = t & 1;
        const uint16_t* la = lA[p];
        const uint16_t* lb = lB[p];
        const bool pre = (t < 63);

        s16x8 a0[4][2], a1[4][2], b0[2][2], b1[2][2];

        // ---- P0: read a0 (i 0..3) + b0 (j 0..1); issue next-tile A regs + B DMA ----
#pragma unroll
        for (int kk = 0; kk < 2; kk++) {
#pragma unroll
            for (int i = 0; i < 4; i++) a0[i][kk] = frag(la, wm + i * 16 + col, kk * 4 + quad);
#pragma unroll
            for (int j = 0; j < 2; j++) b0[j][kk] = frag(lb, wn + j * 16 + col, kk * 4 + quad);
        }
        if (pre) { const int kb = (t + 1) * 64; loadA(kb); issueB(kb, p ^ 1); }
        __builtin_amdgcn_s_barrier();
        asm volatile("s_waitcnt lgkmcnt(0)" ::: "memory");
        __builtin_amdgcn_sched_barrier(0);
        __builtin_amdgcn_s_setprio(1);
#pragma unroll
        for (int kk = 0; kk < 2; kk++)
#pragma unroll
            for (int i = 0; i < 4; i++)
#pragma unroll
                for (int j = 0; j < 2; j++)
                    acc[i][j] = __builtin_amdgcn_mfma_f32_16x16x32_bf16(a0[i][kk], b0[j][kk], acc[i][j], 0, 0, 0);
        __builtin_amdgcn_s_setprio(0);
        __builtin_amdgcn_sched_barrier(0);
        __builtin_amdgcn_s_barrier();

        // ---- P1: read b1 (j 2..3); mfma (a0,b1) ----
#pragma unroll
        for (int kk = 0; kk < 2; kk++)
#pragma unroll
            for (int j = 0; j < 2; j++) b1[j][kk] = frag(lb, wn + (j + 2) * 16 + col, kk * 4 + quad);
        __builtin_amdgcn_s_barrier();
        asm volatile("s_waitcnt lgkmcnt(0)" ::: "memory");
        __builtin_amdgcn_sched_barrier(0);
        __builtin_amdgcn_s_setprio(1);
#pragma unroll
        for (int kk = 0; kk < 2; kk++)
#pragma unroll
            for (int i = 0; i < 4; i++)
#pragma unroll
                for (int j = 0; j < 2; j++)
                    acc[i][j + 2] = __builtin_amdgcn_mfma_f32_16x16x32_bf16(a0[i][kk], b1[j][kk], acc[i][j + 2], 0, 0, 0);
        __builtin_amdgcn_s_setprio(0);
        __builtin_amdgcn_sched_barrier(0);
        __builtin_amdgcn_s_barrier();

        // ---- P2: read a1 (i 4..7); mfma (a1,b1) ----
#pragma unroll
        for (int kk = 0; kk < 2; kk++)
#pragma unroll
            for (int i = 0; i < 4; i++) a1[i][kk] = frag(la, wm + (i + 4) * 16 + col, kk * 4 + quad);
        __builtin_amdgcn_s_barrier();
        asm volatile("s_waitcnt lgkmcnt(0)" ::: "memory");
        __builtin_amdgcn_sched_barrier(0);
        __builtin_amdgcn_s_setprio(1);
#pragma unroll
        for (int kk = 0; kk < 2; kk++)
#pragma unroll
            for (int i = 0; i < 4; i++)
#pragma unroll
                for (int j = 0; j < 2; j++)
                    acc[i + 4][j + 2] = __builtin_amdgcn_mfma_f32_16x16x32_bf16(a1[i][kk], b1[j][kk], acc[i + 4][j + 2], 0, 0, 0);
        __builtin_amdgcn_s_setprio(0);
        __builtin_amdgcn_sched_barrier(0);
        __builtin_amdgcn_s_barrier();

        // ---- P3: mfma (a1,b0); pack A(t+1) -> lA[p^1]; once-per-tile drain ----
        __builtin_amdgcn_s_setprio(1);
#pragma unroll
        for (int kk = 0; kk < 2; kk++)
#pragma unroll
            for (int i = 0; i < 4; i++)
#pragma unroll
                for (int j = 0; j < 2; j++)
                    acc[i + 4][j] = __builtin_amdgcn_mfma_f32_16x16x32_bf16(a1[i][kk], b0[j][kk], acc[i + 4][j], 0, 0, 0);
        __builtin_amdgcn_s_setprio(0);
        __builtin_amdgcn_sched_barrier(0);
        if (pre) {
            packA(p ^ 1);   // implicit vmcnt wait for A regs only (B DMA issued later stays counted)
            asm volatile("s_waitcnt vmcnt(0) lgkmcnt(0)" ::: "memory");  // B DMA issued at P0: ~3 phases old, free
        }
        __builtin_amdgcn_s_barrier();
    }

    // ---- fused epilogue: bias + tanh + Vw-dot, reduce 64 n-cols -> u[m] ----
    const float wa05 = wa_p[0] * 0.5f;
    float biasv[4], vwv[4];
#pragma unroll
    for (int j = 0; j < 4; j++) {
        int n = nBase + wn + j * 16 + col;
        biasv[j] = bw[n] + bz[n] + wa05;
        vwv[j] = Vw[n];
    }
#pragma unroll
    for (int i = 0; i < 8; i++) {
#pragma unroll
        for (int r = 0; r < 4; r++) {
            float sv = 0.f;
#pragma unroll
            for (int j = 0; j < 4; j++) {
                float xv = acc[i][j][r] + biasv[j];
                sv += fast_tanh(xv) * vwv[j];
            }
            // reduce across the 16 n-cols held by this quad group (D: col=lane&15)
            sv += __shfl_xor(sv, 8);
            sv += __shfl_xor(sv, 4);
            sv += __shfl_xor(sv, 2);
            sv += __shfl_xor(sv, 1);
            if (col == 0)
                atomicAdd(&u[mBase + wm + i * 16 + quad * 4 + r], sv);
        }
    }
}

// ------------------- softmax over S per batch, in-place on u=d_out -------------------
__global__ void softmax_kernel(float* __restrict__ u) {
    const int b = blockIdx.x;
    const int t = threadIdx.x;  // 256 threads, 8 s-values each
    __shared__ float redm[4], reds[4];
    float v[8];
    float mx = -1e30f;
#pragma unroll
    for (int k = 0; k < 8; k++) {
        v[k] = u[(size_t)(t + k * 256) * B_DIM + b];
        mx = fmaxf(mx, v[k]);
    }
#pragma unroll
    for (int off = 32; off >= 1; off >>= 1) mx = fmaxf(mx, __shfl_xor(mx, off));
    if ((t & 63) == 0) redm[t >> 6] = mx;
    __syncthreads();
    mx = fmaxf(fmaxf(redm[0], redm[1]), fmaxf(redm[2], redm[3]));
    float s = 0.f;
#pragma unroll
    for (int k = 0; k < 8; k++) {
        v[k] = __expf(v[k] - mx);
        s += v[k];
    }
#pragma unroll
    for (int off = 32; off >= 1; off >>= 1) s += __shfl_xor(s, off);
    if ((t & 63) == 0) reds[t >> 6] = s;
    __syncthreads();
    s = reds[0] + reds[1] + reds[2] + reds[3];
    float inv = 1.0f / s;
#pragma unroll
    for (int k = 0; k < 8; k++)
        u[(size_t)(t + k * 256) * B_DIM + b] = v[k] * inv;
}

extern "C" void kernel_launch(void* const* d_in, const int* in_sizes, int n_in,
                              void* d_out, int out_size, void* d_ws, size_t ws_size,
                              hipStream_t stream) {
    const float* hidden = (const float*)d_in[0];
    const float* z = (const float*)d_in[1];
    const float* Ww = (const float*)d_in[2];
    const float* bw = (const float*)d_in[3];
    const float* Wz = (const float*)d_in[4];
    const float* bz = (const float*)d_in[5];
    const float* Vw = (const float*)d_in[6];
    // d_in[7] = vb: constant shift over the softmax axis -> no effect, dropped
    const float* wa = (const float*)d_in[8];
    float* out = (float*)d_out;

    char* ws = (char*)d_ws;
    const size_t bBytes = (size_t)V_DIM * K_HALF * 2;  // 4 MiB per B matrix (bf16)
    uint16_t* wsB1 = (uint16_t*)ws;
    uint16_t* wsB2 = (uint16_t*)(ws + bBytes);

    // u lives in d_out (zero it; GEMM accumulates, softmax finishes in-place)
    hipMemsetAsync(d_out, 0, (size_t)M_DIM * sizeof(float), stream);

    transposeB<<<dim3(K_HALF / 32, V_DIM / 32, 2), 256, 0, stream>>>(Ww, Wz, wsB1, wsB2);

    gemm_kernel<<<dim3((M_DIM / 256) * (V_DIM / 256)), 512, 0, stream>>>(
        hidden, z, wsB1, wsB2, bw, bz, wa, Vw, out);

    softmax_kernel<<<B_DIM, 256, 0, stream>>>(out);
}

// Round 2
// 841.442 us; speedup vs baseline: 1.0183x; 1.0183x over previous
//
#include <hip/hip_runtime.h>
#include <hip/hip_bf16.h>
#include <stdint.h>

#define S_DIM 2048
#define B_DIM 16
#define H2_DIM 2048
#define V_DIM 1024
#define M_DIM (S_DIM * B_DIM)   // 32768
#define K_HALF 2048
#define K_TOT 4096

typedef __attribute__((ext_vector_type(8))) short s16x8;   // 8 bf16 (4 VGPRs) MFMA frag
typedef __attribute__((ext_vector_type(4))) float f32x4;   // MFMA accumulator

// fp32 -> bf16 round-to-nearest-even (scalar, used in transposeB only)
__device__ __forceinline__ uint16_t f2bf(float f) {
    union { float f; uint32_t u; } c; c.f = f;
    uint32_t u = c.u;
    u += 0x7fffu + ((u >> 16) & 1u);
    return (uint16_t)(u >> 16);
}

// pack 2 fp32 -> 2 bf16 (round-to-nearest), 3 VALU ops: 2 adds + 1 v_perm_b32
__device__ __forceinline__ uint32_t pack_bf16_rn(float a, float b) {
    union { float f; uint32_t u; } ca, cb; ca.f = a; cb.f = b;
    uint32_t ua = ca.u + 0x8000u;
    uint32_t ub = cb.u + 0x8000u;
    return __builtin_amdgcn_perm(ub, ua, 0x07060302u);
}

__device__ __forceinline__ float fast_tanh(float x) {
    float e = __expf(2.0f * x);
    return 1.0f - 2.0f / (e + 1.0f);
}

// async global->LDS, 16B per lane. LDS dest is wave-uniform base + lane*16.
__device__ __forceinline__ void gload_lds16(const void* g, void* l) {
    __builtin_amdgcn_global_load_lds(
        (__attribute__((address_space(1))) void*)(uintptr_t)g,
        (__attribute__((address_space(3))) void*)(uint32_t)(uintptr_t)l,
        16, 0, 0);
}

// ------------- transpose+convert Ww/Wz [K][V] fp32 -> B^T [V][K] bf16 -------------
__global__ void transposeB(const float* __restrict__ Ww, const float* __restrict__ Wz,
                           uint16_t* __restrict__ B1, uint16_t* __restrict__ B2) {
    __shared__ float tile[32][33];
    const float* src = blockIdx.z ? Wz : Ww;
    uint16_t* dst = blockIdx.z ? B2 : B1;
    int k0 = blockIdx.x * 32, v0 = blockIdx.y * 32;
    int tv = threadIdx.x & 31, tk = threadIdx.x >> 5;  // tk in 0..7
#pragma unroll
    for (int r = 0; r < 4; r++) {
        int k = tk * 4 + r;
        tile[k][tv] = src[(size_t)(k0 + k) * V_DIM + v0 + tv];
    }
    __syncthreads();
#pragma unroll
    for (int r = 0; r < 4; r++) {
        int v = tk * 4 + r;
        dst[(size_t)(v0 + v) * K_HALF + k0 + tv] = f2bf(tile[tv][v]);
    }
}

// ---------------------------------- fused GEMM ----------------------------------
// 256x256 tile, 8 waves (2m x 4n), per-wave 128m x 64n, BK=64, 4-subphase schedule.
// Counted-vmcnt discipline (T4): the main loop NEVER drains vmcnt to 0.
//   - B(t+1) DMA'd to LDS at P0 of tile t, waited with vmcnt(8) at P3 (4 phases of
//     cover); the 8 newest ops (A(t+2) reg-loads) stay in flight across the barrier.
//   - A(t+2) fp32 global->regs issued at P3 of tile t, consumed by packA at P3 of
//     tile t+1 (a full tile of cover).
// Epilogue: u[m] += sum_n tanh(C[m,n]+bias[n]) * Vw[n]
__global__ __launch_bounds__(512, 2) void gemm_kernel(
    const float* __restrict__ F1, const float* __restrict__ F2,
    const uint16_t* __restrict__ B1, const uint16_t* __restrict__ B2,
    const float* __restrict__ bw, const float* __restrict__ bz,
    const float* __restrict__ wa_p, const float* __restrict__ Vw,
    float* __restrict__ u) {
    __shared__ __align__(16) uint16_t lA[2][256 * 64];   // 2 x 32 KB
    __shared__ __align__(16) uint16_t lB[2][256 * 64];   // 2 x 32 KB

    const int tid = threadIdx.x;
    const int lane = tid & 63;
    const int wv = tid >> 6;                      // wave 0..7, 2m x 4n grid
    const int wm = (wv >> 2) * 128, wn = (wv & 3) * 64;
    // XCD swizzle: the 4 n-tiles of an m-tile share id&7 -> same XCD -> A K-slices
    // stay L2-warm. 512 blocks = 2 exact dispatch rounds at 1 block/CU.
    const int id = blockIdx.x;                    // grid = 512
    const int nBase = ((id >> 3) & 3) * 256;
    const int mBase = ((id & 7) + ((id >> 5) << 3)) * 256;
    const int lr = lane >> 3;                     // row within 8-row staging group
    const int lc = lane & 7;                      // LDS chunk slot
    const int cg = lc ^ lr;                       // swizzled global chunk
    const int col = lane & 15, quad = lane >> 4;

    f32x4 acc[8][4] = {};

    // staging base pointers (this thread's fixed row/chunk assignment)
    const float* aRow[2];
    const uint16_t* bRow[2];
    {
        const size_t aoff = (size_t)(mBase + wv * 32 + lr) * K_HALF + cg * 8;
        aRow[0] = F1 + aoff; aRow[1] = F2 + aoff;
        const size_t boff = (size_t)(nBase + wv * 32 + lr) * K_HALF + cg * 8;
        bRow[0] = B1 + boff; bRow[1] = B2 + boff;
    }

    float4 ar[4][2];   // A prefetch registers (one K-tile ahead)

    auto loadA = [&](int kb) {
        const float* base = aRow[kb >> 11] + (kb & (K_HALF - 1));
#pragma unroll
        for (int j = 0; j < 4; j++) {
            const float* gp = base + (size_t)(j * 8) * K_HALF;
            ar[j][0] = ((const float4*)gp)[0];
            ar[j][1] = ((const float4*)gp)[1];
        }
    };
    auto issueB = [&](int kb, int p) {
        const uint16_t* base = bRow[kb >> 11] + (kb & (K_HALF - 1));
#pragma unroll
        for (int j = 0; j < 4; j++)
            gload_lds16(base + (size_t)(j * 8) * K_HALF, &lB[p][(wv * 32 + j * 8) * 64]);
    };
    auto packA = [&](int p) {
#pragma unroll
        for (int j = 0; j < 4; j++) {
            uint4 w = make_uint4(pack_bf16_rn(ar[j][0].x, ar[j][0].y),
                                 pack_bf16_rn(ar[j][0].z, ar[j][0].w),
                                 pack_bf16_rn(ar[j][1].x, ar[j][1].y),
                                 pack_bf16_rn(ar[j][1].z, ar[j][1].w));
            *(uint4*)&lA[p][(wv * 32 + j * 8 + lr) * 64 + lc * 8] = w;
        }
    };
    // LDS[row][chunk c] holds global chunk c ^ (row&7): read with the same XOR
    auto frag = [&](const uint16_t* l, int row, int cidx) -> s16x8 {
        return *(const s16x8*)&l[row * 64 + ((cidx ^ (row & 7)) << 3)];
    };

    // prologue: fill buffer 0, prefetch A(1), keep A(1) in flight across the barrier
    loadA(0);
    issueB(0, 0);
    packA(0);                    // implicit wait: A(0) regs (vmcnt counted by compiler)
    loadA(64);                   // A(1) -> regs, stays outstanding
    asm volatile("s_waitcnt vmcnt(8) lgkmcnt(0)" ::: "memory");  // drain B(0) only
    __builtin_amdgcn_s_barrier();

#pragma unroll 1
    for (int t = 0; t < 64; ++t) {
        const int p = t & 1;
        const uint16_t* la = lA[p];
        const uint16_t* lb = lB[p];

        s16x8 a0[4][2], a1[4][2], b0[2][2], b1[2][2];

        // ---- P0: read a0 (i 0..3) + b0 (j 0..1); issue B(t+1) DMA ----
#pragma unroll
        for (int kk = 0; kk < 2; kk++) {
#pragma unroll
            for (int i = 0; i < 4; i++) a0[i][kk] = frag(la, wm + i * 16 + col, kk * 4 + quad);
#pragma unroll
            for (int j = 0; j < 2; j++) b0[j][kk] = frag(lb, wn + j * 16 + col, kk * 4 + quad);
        }
        if (t < 63) issueB((t + 1) * 64, p ^ 1);
        __builtin_amdgcn_s_barrier();
        asm volatile("s_waitcnt lgkmcnt(0)" ::: "memory");
        __builtin_amdgcn_sched_barrier(0);
        __builtin_amdgcn_s_setprio(1);
#pragma unroll
        for (int kk = 0; kk < 2; kk++)
#pragma unroll
            for (int i = 0; i < 4; i++)
#pragma unroll
                for (int j = 0; j < 2; j++)
                    acc[i][j] = __builtin_amdgcn_mfma_f32_16x16x32_bf16(a0[i][kk], b0[j][kk], acc[i][j], 0, 0, 0);
        __builtin_amdgcn_s_setprio(0);
        __builtin_amdgcn_sched_barrier(0);
        __builtin_amdgcn_s_barrier();

        // ---- P1: read b1 (j 2..3); mfma (a0,b1) ----
#pragma unroll
        for (int kk = 0; kk < 2; kk++)
#pragma unroll
            for (int j = 0; j < 2; j++) b1[j][kk] = frag(lb, wn + (j + 2) * 16 + col, kk * 4 + quad);
        __builtin_amdgcn_s_barrier();
        asm volatile("s_waitcnt lgkmcnt(0)" ::: "memory");
        __builtin_amdgcn_sched_barrier(0);
        __builtin_amdgcn_s_setprio(1);
#pragma unroll
        for (int kk = 0; kk < 2; kk++)
#pragma unroll
            for (int i = 0; i < 4; i++)
#pragma unroll
                for (int j = 0; j < 2; j++)
                    acc[i][j + 2] = __builtin_amdgcn_mfma_f32_16x16x32_bf16(a0[i][kk], b1[j][kk], acc[i][j + 2], 0, 0, 0);
        __builtin_amdgcn_s_setprio(0);
        __builtin_amdgcn_sched_barrier(0);
        __builtin_amdgcn_s_barrier();

        // ---- P2: read a1 (i 4..7); mfma (a1,b1) ----
#pragma unroll
        for (int kk = 0; kk < 2; kk++)
#pragma unroll
            for (int i = 0; i < 4; i++) a1[i][kk] = frag(la, wm + (i + 4) * 16 + col, kk * 4 + quad);
        __builtin_amdgcn_s_barrier();
        asm volatile("s_waitcnt lgkmcnt(0)" ::: "memory");
        __builtin_amdgcn_sched_barrier(0);
        __builtin_amdgcn_s_setprio(1);
#pragma unroll
        for (int kk = 0; kk < 2; kk++)
#pragma unroll
            for (int i = 0; i < 4; i++)
#pragma unroll
                for (int j = 0; j < 2; j++)
                    acc[i + 4][j + 2] = __builtin_amdgcn_mfma_f32_16x16x32_bf16(a1[i][kk], b1[j][kk], acc[i + 4][j + 2], 0, 0, 0);
        __builtin_amdgcn_s_setprio(0);
        __builtin_amdgcn_sched_barrier(0);
        __builtin_amdgcn_s_barrier();

        // ---- P3: mfma (a1,b0); pack A(t+1) -> lA[p^1]; issue A(t+2); counted wait ----
        __builtin_amdgcn_s_setprio(1);
#pragma unroll
        for (int kk = 0; kk < 2; kk++)
#pragma unroll
            for (int i = 0; i < 4; i++)
#pragma unroll
                for (int j = 0; j < 2; j++)
                    acc[i + 4][j] = __builtin_amdgcn_mfma_f32_16x16x32_bf16(a1[i][kk], b0[j][kk], acc[i + 4][j], 0, 0, 0);
        __builtin_amdgcn_s_setprio(0);
        __builtin_amdgcn_sched_barrier(0);
        if (t < 63) {
            packA(p ^ 1);            // implicit wait: A(t+1) regs, issued a full tile ago
            if (t < 62) {
                loadA((t + 2) * 64); // A(t+2) -> regs, 8 newest vmem ops
                // wait everything EXCEPT the 8 newest: drains B(t+1) (issued at P0,
                // 4 phases old -> free); A(t+2) stays in flight across the barrier.
                asm volatile("s_waitcnt vmcnt(8) lgkmcnt(0)" ::: "memory");
            } else {
                // t == 62: no A(64); only B(63) outstanding
                asm volatile("s_waitcnt vmcnt(0) lgkmcnt(0)" ::: "memory");
            }
        }
        __builtin_amdgcn_s_barrier();
    }

    // ---- fused epilogue: bias + tanh + Vw-dot, reduce 64 n-cols -> u[m] ----
    const float wa05 = wa_p[0] * 0.5f;
    float biasv[4], vwv[4];
#pragma unroll
    for (int j = 0; j < 4; j++) {
        int n = nBase + wn + j * 16 + col;
        biasv[j] = bw[n] + bz[n] + wa05;
        vwv[j] = Vw[n];
    }
#pragma unroll
    for (int i = 0; i < 8; i++) {
#pragma unroll
        for (int r = 0; r < 4; r++) {
            float sv = 0.f;
#pragma unroll
            for (int j = 0; j < 4; j++) {
                float xv = acc[i][j][r] + biasv[j];
                sv += fast_tanh(xv) * vwv[j];
            }
            // reduce across the 16 n-cols held by this quad group (D: col=lane&15)
            sv += __shfl_xor(sv, 8);
            sv += __shfl_xor(sv, 4);
            sv += __shfl_xor(sv, 2);
            sv += __shfl_xor(sv, 1);
            if (col == 0)
                atomicAdd(&u[mBase + wm + i * 16 + quad * 4 + r], sv);
        }
    }
}

// ------------------- softmax over S per batch, in-place on u=d_out -------------------
__global__ void softmax_kernel(float* __restrict__ u) {
    const int b = blockIdx.x;
    const int t = threadIdx.x;  // 256 threads, 8 s-values each
    __shared__ float redm[4], reds[4];
    float v[8];
    float mx = -1e30f;
#pragma unroll
    for (int k = 0; k < 8; k++) {
        v[k] = u[(size_t)(t + k * 256) * B_DIM + b];
        mx = fmaxf(mx, v[k]);
    }
#pragma unroll
    for (int off = 32; off >= 1; off >>= 1) mx = fmaxf(mx, __shfl_xor(mx, off));
    if ((t & 63) == 0) redm[t >> 6] = mx;
    __syncthreads();
    mx = fmaxf(fmaxf(redm[0], redm[1]), fmaxf(redm[2], redm[3]));
    float s = 0.f;
#pragma unroll
    for (int k = 0; k < 8; k++) {
        v[k] = __expf(v[k] - mx);
        s += v[k];
    }
#pragma unroll
    for (int off = 32; off >= 1; off >>= 1) s += __shfl_xor(s, off);
    if ((t & 63) == 0) reds[t >> 6] = s;
    __syncthreads();
    s = reds[0] + reds[1] + reds[2] + reds[3];
    float inv = 1.0f / s;
#pragma unroll
    for (int k = 0; k < 8; k++)
        u[(size_t)(t + k * 256) * B_DIM + b] = v[k] * inv;
}

extern "C" void kernel_launch(void* const* d_in, const int* in_sizes, int n_in,
                              void* d_out, int out_size, void* d_ws, size_t ws_size,
                              hipStream_t stream) {
    const float* hidden = (const float*)d_in[0];
    const float* z = (const float*)d_in[1];
    const float* Ww = (const float*)d_in[2];
    const float* bw = (const float*)d_in[3];
    const float* Wz = (const float*)d_in[4];
    const float* bz = (const float*)d_in[5];
    const float* Vw = (const float*)d_in[6];
    // d_in[7] = vb: constant shift over the softmax axis -> no effect, dropped
    const float* wa = (const float*)d_in[8];
    float* out = (float*)d_out;

    char* ws = (char*)d_ws;
    const size_t bBytes = (size_t)V_DIM * K_HALF * 2;  // 4 MiB per B matrix (bf16)
    uint16_t* wsB1 = (uint16_t*)ws;
    uint16_t* wsB2 = (uint16_t*)(ws + bBytes);

    // u lives in d_out (zero it; GEMM accumulates, softmax finishes in-place)
    hipMemsetAsync(d_out, 0, (size_t)M_DIM * sizeof(float), stream);

    transposeB<<<dim3(K_HALF / 32, V_DIM / 32, 2), 256, 0, stream>>>(Ww, Wz, wsB1, wsB2);

    gemm_kernel<<<dim3((M_DIM / 256) * (V_DIM / 256)), 512, 0, stream>>>(
        hidden, z, wsB1, wsB2, bw, bz, wa, Vw, out);

    softmax_kernel<<<B_DIM, 256, 0, stream>>>(out);
}